// Round 3
// baseline (251.271 us; speedup 1.0000x reference)
//
#include <hip/hip_runtime.h>
#include <hip/hip_bf16.h>
#include <cstdint>

typedef __attribute__((ext_vector_type(8))) short bf16x8;   // 8 bf16 in 4 VGPRs
typedef __attribute__((ext_vector_type(4))) float f32x4;
typedef unsigned short ushortT;
typedef unsigned int uintT;

#define LOG2E 1.4426950408889634f

static __device__ __forceinline__ ushortT f2bf(float x) {
  uintT u = __builtin_bit_cast(uintT, x);
  u += 0x7fffu + ((u >> 16) & 1u);          // RNE
  return (ushortT)(u >> 16);
}

static __device__ __forceinline__ float exp2_fast(float x) {
#if __has_builtin(__builtin_amdgcn_exp2f)
  return __builtin_amdgcn_exp2f(x);
#else
  float r;
  asm volatile("v_exp_f32 %0, %1" : "=v"(r) : "v"(x));
  return r;
#endif
}

// ---------------- Kernel 0: WvT[d][k] = bf16(Wv[k][d]), 1024x1024 ----------------
__global__ __launch_bounds__(256) void k_transpose_wv(const float* __restrict__ Wv,
                                                      ushortT* __restrict__ WvT) {
  __shared__ float tile[64][65];
  int bd = blockIdx.x * 64;   // d tile
  int bk = blockIdx.y * 64;   // k tile
  int t = threadIdx.x;
  int col = t & 63;
  int r0 = t >> 6;            // 0..3
  for (int r = r0; r < 64; r += 4)
    tile[r][col] = Wv[(size_t)(bk + r) * 1024 + bd + col];
  __syncthreads();
  for (int r = r0; r < 64; r += 4)
    WvT[(size_t)(bd + r) * 1024 + bk + col] = f2bf(tile[col][r]);
}

// ---------------- Kernel 1: vt[b][d][j] = bf16( (value @ Wv + bv)[b,j,d] ) ----------------
// GEMM: M=8192 rows (b,j), N=1024 (d), K=1024. 128x128 tile, BK=32, 4 waves.
__global__ __launch_bounds__(256) void k_vproj(const float* __restrict__ value,
                                               const ushortT* __restrict__ WvT,
                                               const float* __restrict__ bv,
                                               ushortT* __restrict__ vt) {
  __shared__ ushortT smem[128 * 136];        // 34.8 KB; staging + epilogue reuse
  ushortT* As = smem;                        // [128][40] bf16, pitch 40 (80B, 16B-aligned)
  ushortT* Bs = smem + 5120;                 // [128][40]
  int t = threadIdx.x;
  int l = t & 63, w = t >> 6;
  int gj0 = blockIdx.x * 128;                // global row (b*2048+j)
  int n0 = blockIdx.y * 128;                 // d
  int b = gj0 >> 11, j0 = gj0 & 2047;
  int wr = (w >> 1) * 64, wc = (w & 1) * 64;

  f32x4 acc[4][4];
#pragma unroll
  for (int i = 0; i < 4; ++i)
#pragma unroll
    for (int j = 0; j < 4; ++j) acc[i][j] = (f32x4)0.0f;

  for (int kt = 0; kt < 32; ++kt) {
    // stage A: value rows gj0..+127, cols kt*32..+31, f32 -> bf16
    {
      int seg = t & 7;
#pragma unroll
      for (int pass = 0; pass < 4; ++pass) {
        int r = pass * 32 + (t >> 3);
        float4 v4 = *reinterpret_cast<const float4*>(value + (size_t)(gj0 + r) * 1024 + kt * 32 + seg * 4);
        ushort4 u;
        u.x = f2bf(v4.x); u.y = f2bf(v4.y); u.z = f2bf(v4.z); u.w = f2bf(v4.w);
        *reinterpret_cast<ushort4*>(&As[r * 40 + seg * 4]) = u;
      }
    }
    // stage B: WvT rows n0..+127 (d), cols kt*32..+31 (already bf16)
    {
      int seg = t & 3;
#pragma unroll
      for (int pass = 0; pass < 2; ++pass) {
        int r = pass * 64 + (t >> 2);
        uint4 v = *reinterpret_cast<const uint4*>(WvT + (size_t)(n0 + r) * 1024 + kt * 32 + seg * 8);
        *reinterpret_cast<uint4*>(&Bs[r * 40 + seg * 8]) = v;
      }
    }
    __syncthreads();
    bf16x8 af[4], bfr[4];
#pragma unroll
    for (int i = 0; i < 4; ++i)
      af[i] = *reinterpret_cast<const bf16x8*>(&As[(wr + 16 * i + (l & 15)) * 40 + (l >> 4) * 8]);
#pragma unroll
    for (int j = 0; j < 4; ++j)
      bfr[j] = *reinterpret_cast<const bf16x8*>(&Bs[(wc + 16 * j + (l & 15)) * 40 + (l >> 4) * 8]);
#pragma unroll
    for (int i = 0; i < 4; ++i)
#pragma unroll
      for (int j = 0; j < 4; ++j)
        acc[i][j] = __builtin_amdgcn_mfma_f32_16x16x32_bf16(af[i], bfr[j], acc[i][j], 0, 0, 0);
    __syncthreads();
  }

  // epilogue: transpose via LDS, Ct[d_local][j_local], pitch 136
#pragma unroll
  for (int jj = 0; jj < 4; ++jj) {
    int dl = wc + 16 * jj + (l & 15);
    float bvv = bv[n0 + dl];
#pragma unroll
    for (int ii = 0; ii < 4; ++ii) {
      int jl = wr + 16 * ii + (l >> 4) * 4;
      ushort4 u;
      u.x = f2bf(acc[ii][jj].x + bvv);
      u.y = f2bf(acc[ii][jj].y + bvv);
      u.z = f2bf(acc[ii][jj].z + bvv);
      u.w = f2bf(acc[ii][jj].w + bvv);
      *reinterpret_cast<ushort4*>(&smem[dl * 136 + jl]) = u;
    }
  }
  __syncthreads();
  {
    int dl = t >> 1, half = t & 1;
#pragma unroll
    for (int n = 0; n < 8; ++n) {
      uint4 v = *reinterpret_cast<const uint4*>(&smem[dl * 136 + half * 64 + n * 8]);
      *reinterpret_cast<uint4*>(vt + (size_t)(b * 1024 + n0 + dl) * 2048 + j0 + half * 64 + n * 8) = v;
    }
  }
}

// ---------------- Kernel 2: attention ----------------
// grid (Sq/64, B, H), 256 threads (4 waves). Per block: 64 q-rows of one (h,b).
// p_ij = exp(c_i*kx_j - m_i), c_i = (A_h*qx_i + Bk_h)/8, m_i = max(c_i*kmax, c_i*kmin).
// out[i][d] = (sum_j p_ij * vt[b][h*64+d][j]) / Z_i
__global__ __launch_bounds__(256) void k_attn(const float* __restrict__ query,
                                              const float* __restrict__ key,
                                              const float* __restrict__ Wq,
                                              const float* __restrict__ bq,
                                              const float* __restrict__ Wk,
                                              const ushortT* __restrict__ vt,
                                              float* __restrict__ out) {
  __shared__ float kx_s[2048];
  __shared__ float cl[64], ml[64];
  __shared__ float wred[16];
  __shared__ float Zp[256];
  __shared__ float rZ[64];
  __shared__ ushortT P_lds[64 * 136];
  __shared__ ushortT V_lds[64 * 136];

  int t = threadIdx.x;
  int l = t & 63, w = t >> 6;
  int q0 = blockIdx.x * 64;
  int b = blockIdx.y;
  int h = blockIdx.z;

  // head scalars (redundant per thread; broadcast loads)
  float Ah = 0.f, Bkh = 0.f;
#pragma unroll 8
  for (int d = 0; d < 64; ++d) {
    float wk = Wk[h * 64 + d];
    Ah = fmaf(Wq[h * 64 + d], wk, Ah);
    Bkh = fmaf(bq[h * 64 + d], wk, Bkh);
  }

  // load kx into LDS, reduce min/max
  float kmx = -1e30f, kmn = 1e30f;
  for (int j = t; j < 2048; j += 256) {
    float v = key[b * 2048 + j];
    kx_s[j] = v;
    kmx = fmaxf(kmx, v); kmn = fminf(kmn, v);
  }
#pragma unroll
  for (int off = 32; off > 0; off >>= 1) {
    kmx = fmaxf(kmx, __shfl_xor(kmx, off));
    kmn = fminf(kmn, __shfl_xor(kmn, off));
  }
  if (l == 0) { wred[w] = kmx; wred[8 + w] = kmn; }
  __syncthreads();
  kmx = fmaxf(fmaxf(wred[0], wred[1]), fmaxf(wred[2], wred[3]));
  kmn = fminf(fminf(wred[8], wred[9]), fminf(wred[10], wred[11]));

  if (t < 64) {
    float qx = query[b * 2048 + q0 + t];
    float c = (Ah * qx + Bkh) * 0.125f;
    float m = fmaxf(c * kmx, c * kmn);
    cl[t] = c * LOG2E;
    ml[t] = m * LOG2E;
  }
  __syncthreads();

  f32x4 acc[4];
#pragma unroll
  for (int d = 0; d < 4; ++d) acc[d] = (f32x4)0.0f;
  float zpart = 0.f;
  int pi = t >> 2, pq = t & 3;              // P-gen: row pi, col strip pq*32
  float cli = cl[pi], mli = ml[pi];

  for (int kt = 0; kt < 16; ++kt) {
    // stage V tile: 64 d-rows x 128 k, bf16 (K-major rows of vt)
    {
      int seg = t & 15, r4 = t >> 4;
#pragma unroll
      for (int pass = 0; pass < 4; ++pass) {
        int r = pass * 16 + r4;
        uint4 v = *reinterpret_cast<const uint4*>(vt + (size_t)(b * 1024 + h * 64 + r) * 2048 + kt * 128 + seg * 8);
        *reinterpret_cast<uint4*>(&V_lds[r * 136 + seg * 8]) = v;
      }
    }
    // generate P tile: 64 rows x 128 cols, bf16 + fp32 Z partials
    {
      int jbase = kt * 128 + pq * 32;
#pragma unroll
      for (int n = 0; n < 16; ++n) {
        float x0 = kx_s[jbase + 2 * n];
        float x1 = kx_s[jbase + 2 * n + 1];
        float p0 = exp2_fast(fmaf(cli, x0, -mli));
        float p1 = exp2_fast(fmaf(cli, x1, -mli));
        zpart += p0 + p1;
        uintT pk = (uintT)f2bf(p0) | ((uintT)f2bf(p1) << 16);
        *reinterpret_cast<uintT*>(&P_lds[pi * 136 + pq * 32 + 2 * n]) = pk;
      }
    }
    __syncthreads();
#pragma unroll
    for (int kk = 0; kk < 4; ++kk) {
      bf16x8 a = *reinterpret_cast<const bf16x8*>(&P_lds[(16 * w + (l & 15)) * 136 + kk * 32 + (l >> 4) * 8]);
#pragma unroll
      for (int db = 0; db < 4; ++db) {
        bf16x8 bb = *reinterpret_cast<const bf16x8*>(&V_lds[(16 * db + (l & 15)) * 136 + kk * 32 + (l >> 4) * 8]);
        acc[db] = __builtin_amdgcn_mfma_f32_16x16x32_bf16(a, bb, acc[db], 0, 0, 0);
      }
    }
    __syncthreads();
  }

  Zp[t] = zpart;
  __syncthreads();
  if (t < 64) {
    float z = Zp[4 * t] + Zp[4 * t + 1] + Zp[4 * t + 2] + Zp[4 * t + 3];
    rZ[t] = 1.0f / z;
  }
  __syncthreads();

  // out layout: (H*B, Sq, D), n = h*4 + b
  size_t obase = ((size_t)(h * 4 + b) * 2048 + q0) * 64;
#pragma unroll
  for (int db = 0; db < 4; ++db) {
    int d = db * 16 + (l & 15);
#pragma unroll
    for (int r = 0; r < 4; ++r) {
      int i = 16 * w + (l >> 4) * 4 + r;
      out[obase + (size_t)i * 64 + d] = acc[db][r] * rZ[i];
    }
  }
}

extern "C" void kernel_launch(void* const* d_in, const int* in_sizes, int n_in,
                              void* d_out, int out_size, void* d_ws, size_t ws_size,
                              hipStream_t stream) {
  const float* query = (const float*)d_in[0];
  const float* key   = (const float*)d_in[1];
  const float* value = (const float*)d_in[2];
  const float* Wq    = (const float*)d_in[3];
  // bq = d_in[4], Wk = d_in[5], bk = d_in[6] (bk cancels in softmax)
  const float* bq    = (const float*)d_in[4];
  const float* Wk    = (const float*)d_in[5];
  const float* Wv    = (const float*)d_in[7];
  const float* bv    = (const float*)d_in[8];
  float* out = (float*)d_out;

  ushortT* WvT = (ushortT*)d_ws;                      // 1024*1024 bf16 = 2 MB
  ushortT* vt  = (ushortT*)d_ws + 1024 * 1024;        // 4*1024*2048 bf16 = 16.8 MB

  k_transpose_wv<<<dim3(16, 16), 256, 0, stream>>>(Wv, WvT);
  k_vproj<<<dim3(64, 8), 256, 0, stream>>>(value, WvT, bv, vt);
  k_attn<<<dim3(32, 4, 16), 256, 0, stream>>>(query, key, Wq, bq, Wk, vt, out);
}